// Round 13
// baseline (440.565 us; speedup 1.0000x reference)
//
#include <hip/hip_runtime.h>
#include <hip/hip_bf16.h>
#include <hip/hip_fp16.h>
#include <cstddef>
#include <cstdint>

#define NN 50000
#define EE 400000
#define GG 64
#define MB 391    // ceil(NN/128) (pack granularity)
#define MB2 782   // ceil(NN/64)  (qkv block granularity)

typedef __attribute__((ext_vector_type(8))) _Float16 f16x8;
typedef __attribute__((ext_vector_type(4))) float f32x4;

#define GLOAD_LDS16(g, l) __builtin_amdgcn_global_load_lds( \
    (const __attribute__((address_space(1))) void*)(g), \
    (__attribute__((address_space(3))) void*)(l), 16, 0, 0)

// ---------- helpers ----------
__device__ __forceinline__ unsigned f2key(float f) {
    unsigned u = __float_as_uint(f);
    return (u & 0x80000000u) ? ~u : (u | 0x80000000u);
}
__device__ __forceinline__ float key2f(unsigned k) {
    unsigned u = (k & 0x80000000u) ? (k ^ 0x80000000u) : ~k;
    return __uint_as_float(u);
}

// ---------- prologue: wpack (b<72) | compute_M (b<74) | pack_x (rest) ----------
__global__ __launch_bounds__(256)
void prologue_kernel(const float* __restrict__ lin_qkv, const float* __restrict__ lin_edge,
                     const float* __restrict__ att, const float* __restrict__ x,
                     __half* __restrict__ Wpack, float* __restrict__ M,
                     __half* __restrict__ Apack) {
    int b = blockIdx.x;
    int t = threadIdx.x;
    if (b < 72) {
        // weight packing (fp16): Wpack[l*3+mat][kb 4][kg 4][n 128][8k]
        int g = b * 256 + t;   // [0, 9*2048)
        int lm = g >> 11;
        int r = g & 2047;
        int kb = r >> 9;
        int kg = (r >> 7) & 3;
        int n  = r & 127;
        int k0 = kb * 32 + kg * 8;
        const float* row = lin_qkv + ((size_t)lm * 128 + n) * 128 + k0;
        __half o[8] __attribute__((aligned(16)));
#pragma unroll
        for (int i = 0; i < 8; ++i) o[i] = __float2half(row[i]);
        *reinterpret_cast<uint4*>(Wpack + (size_t)g * 8) = *reinterpret_cast<const uint4*>(o);
    } else if (b < 74) {
        // M[l][h][d] = sum_c lin_edge[l][h*16+c][d] * att[l][2][h][c]
        int g = (b - 72) * 256 + t;
        if (g >= 3 * 128) return;
        int l = g >> 7, r = g & 127, h = r >> 4, d = r & 15;
        const float* le = lin_edge + (size_t)l * 128 * 16;
        const float* av = att + ((l * 3 + 2) * 128) + h * 16;
        float acc = 0.f;
#pragma unroll
        for (int c = 0; c < 16; ++c) acc += le[(h * 16 + c) * 16 + d] * av[c];
        M[g] = acc;
    } else {
        // x packing (fp32 in): Apack[mb][kb 4][kg 4][m 128][8k]
        int s = (b - 74) * 256 + t;   // [0, MB*2048)
        int mb = s >> 11;
        int r  = s & 2047;
        int kb = r >> 9;
        int kg = (r >> 7) & 3;
        int m  = r & 127;
        int node = mb * 128 + m;
        int k0 = kb * 32 + kg * 8;
        size_t slot = ((size_t)(mb * 4 + kb) * 512 + (size_t)kg * 128 + m) * 8;
        __half o[8] __attribute__((aligned(16)));
        if (node < NN) {
            const float* row = x + (size_t)node * 128 + k0;
#pragma unroll
            for (int i = 0; i < 8; ++i) o[i] = __float2half(row[i]);
        } else {
#pragma unroll
            for (int i = 0; i < 8; ++i) o[i] = __float2half(0.f);
        }
        *reinterpret_cast<uint4*>(Apack + slot) = *reinterpret_cast<const uint4*>(o);
    }
}

// ---------- h packing (fp16 in, BN+relu): Apack[mb][kb 4][kg 4][m 128][8k] ----------
__global__ __launch_bounds__(256)
void pack_h_kernel(const __half* __restrict__ hin, const float* __restrict__ sums,
                   const float* __restrict__ scale, const float* __restrict__ shift,
                   __half* __restrict__ Apack) {
    int s = blockIdx.x * 256 + threadIdx.x;   // [0, MB*2048)
    int mb = s >> 11;
    int r  = s & 2047;
    int kb = r >> 9;
    int kg = (r >> 7) & 3;
    int m  = r & 127;
    int node = mb * 128 + m;
    int k0 = kb * 32 + kg * 8;
    size_t slot = ((size_t)(mb * 4 + kb) * 512 + (size_t)kg * 128 + m) * 8;
    __half o[8] __attribute__((aligned(16)));
    if (node < NN) {
        const __half* row = hin + (size_t)node * 128 + k0;
        uint4 raw = *reinterpret_cast<const uint4*>(row);
        const __half* rh = reinterpret_cast<const __half*>(&raw);
#pragma unroll
        for (int i = 0; i < 8; ++i) {
            int c = k0 + i;
            float mu = sums[c] * (1.f / NN);
            float var = sums[128 + c] * (1.f / NN) - mu * mu;
            float v = (__half2float(rh[i]) - mu) * rsqrtf(var + 1e-5f) * scale[c] + shift[c];
            v = v > 0.f ? v : 0.f;
            o[i] = __float2half(v);
        }
    } else {
#pragma unroll
        for (int i = 0; i < 8; ++i) o[i] = __float2half(0.f);
    }
    *reinterpret_cast<uint4*>(Apack + slot) = *reinterpret_cast<const uint4*>(o);
}

// ---------- merged QKV GEMM: 64-row blocks, A staged once, all 3 mats ----------
__global__ __launch_bounds__(256, 4)
void qkv_mfma_kernel(const __half* __restrict__ Apack,
                     const __half* __restrict__ Wpack,
                     int layer,
                     const float* __restrict__ att_l,
                     __half* __restrict__ qa, __half* __restrict__ kv) {
    __shared__ __half As[4][2048];
    __shared__ __half Bb[2][4096];
    const int t = threadIdx.x;
    const int lane = t & 63;
    const int wave = t >> 6;
    const int wr = wave >> 1, wc = wave & 1;
    const int r0 = blockIdx.x * 64;
    const int mbk = blockIdx.x >> 1;
    const int half = blockIdx.x & 1;

    const __half* Abase = Apack + (size_t)mbk * 16384;
    const __half* Bl = Wpack + (size_t)layer * 3 * 16384;

#pragma unroll
    for (int kb = 0; kb < 4; ++kb) {
        const __half* ga = Abase + (size_t)kb * 4096 + (size_t)(t >> 6) * 1024 + half * 512 + (size_t)(t & 63) * 8;
        GLOAD_LDS16(ga, &As[kb][((t >> 6) * 64 + (t & 63)) * 8]);
    }
    {
        const __half* gb = Bl + (size_t)t * 8;
        GLOAD_LDS16(gb, &Bb[0][(size_t)t * 8]);
        GLOAD_LDS16(gb + 2048, &Bb[0][2048 + (size_t)t * 8]);
    }
    __syncthreads();

    const int abase = ((lane >> 4) * 64 + wr * 32 + (lane & 15)) * 8;
    const int bbase = ((lane >> 4) * 128 + wc * 64 + (lane & 15)) * 8;
    const int rowq = (lane >> 4) * 4;

    for (int mat = 0; mat < 3; ++mat) {
        f32x4 acc[2][4];
#pragma unroll
        for (int i = 0; i < 2; ++i)
#pragma unroll
            for (int j = 0; j < 4; ++j) acc[i][j] = (f32x4){0.f, 0.f, 0.f, 0.f};

#pragma unroll
        for (int c = 0; c < 4; ++c) {
            int g = mat * 4 + c;
            if (g < 11) {
                const __half* gb = Bl + (size_t)(g + 1) * 4096 + (size_t)t * 8;
                GLOAD_LDS16(gb, &Bb[(g + 1) & 1][(size_t)t * 8]);
                GLOAD_LDS16(gb + 2048, &Bb[(g + 1) & 1][2048 + (size_t)t * 8]);
            }
            f16x8 aF[2], bF[4];
#pragma unroll
            for (int mf = 0; mf < 2; ++mf)
                aF[mf] = *reinterpret_cast<const f16x8*>(&As[c][abase + mf * 128]);
#pragma unroll
            for (int nf = 0; nf < 4; ++nf)
                bF[nf] = *reinterpret_cast<const f16x8*>(&Bb[g & 1][bbase + nf * 128]);
#pragma unroll
            for (int mf = 0; mf < 2; ++mf)
#pragma unroll
                for (int nf = 0; nf < 4; ++nf)
                    acc[mf][nf] = __builtin_amdgcn_mfma_f32_16x16x32_f16(aF[mf], bF[nf], acc[mf][nf], 0, 0, 0);
            __syncthreads();
        }

        __half* outb = (mat == 0) ? qa : kv;
        const size_t stride = (mat == 0) ? 128 : 256;
        const int coloff = (mat == 2) ? 128 : 0;
        float sc[4];
#pragma unroll
        for (int nf = 0; nf < 4; ++nf) {
            int col = wc * 64 + nf * 16 + (lane & 15);
            sc[nf] = (mat == 2) ? 1.f : att_l[mat * 128 + col];
        }
#pragma unroll
        for (int mf = 0; mf < 2; ++mf) {
            int row0 = r0 + wr * 32 + mf * 16 + rowq;
#pragma unroll
            for (int reg = 0; reg < 4; ++reg) {
                int row = row0 + reg;
                if (row < NN) {
#pragma unroll
                    for (int nf = 0; nf < 4; ++nf) {
                        int col = wc * 64 + nf * 16 + (lane & 15);
                        outb[(size_t)row * stride + coloff + col] = __float2half(acc[mf][nf][reg] * sc[nf]);
                    }
                }
            }
        }
    }
}

// ---------- CSR build ----------
__global__ __launch_bounds__(256)
void deg_count_kernel(const int* __restrict__ ei, int* __restrict__ deg) {
    int e = blockIdx.x * 256 + threadIdx.x;
    if (e < EE) atomicAdd(&deg[ei[EE + e]], 1);
}

__global__ __launch_bounds__(256)
void scan_partial_kernel(const int* __restrict__ deg, int* __restrict__ psum) {
    __shared__ int red[256];
    int i = blockIdx.x * 256 + threadIdx.x;
    red[threadIdx.x] = (i < NN) ? deg[i] : 0;
    __syncthreads();
    for (int o = 128; o > 0; o >>= 1) {
        if (threadIdx.x < o) red[threadIdx.x] += red[threadIdx.x + o];
        __syncthreads();
    }
    if (threadIdx.x == 0) psum[blockIdx.x] = red[0];
}

// scan_final with fused top-level prefix: block b sums psum[0..b) itself
__global__ __launch_bounds__(256)
void scan_final_kernel(const int* __restrict__ deg, const int* __restrict__ psum,
                       int* __restrict__ offs, int* __restrict__ cursor) {
    __shared__ int red[256];
    __shared__ int sh[256];
    int t = threadIdx.x;
    int b = blockIdx.x;
    red[t] = (t < b) ? psum[t] : 0;   // b <= 195 < 196 entries
    __syncthreads();
    for (int o = 128; o > 0; o >>= 1) {
        if (t < o) red[t] += red[t + o];
        __syncthreads();
    }
    int base = red[0];
    int i = b * 256 + t;
    int v = (i < NN) ? deg[i] : 0;
    sh[t] = v;
    __syncthreads();
    for (int o = 1; o < 256; o <<= 1) {
        int add = (t >= o) ? sh[t - o] : 0;
        __syncthreads();
        sh[t] += add;
        __syncthreads();
    }
    if (i < NN) {
        int excl = sh[t] - v + base;
        offs[i] = excl;
        cursor[i] = excl;
    }
}

// ---------- scatter: single 8B store per edge ----------
__global__ __launch_bounds__(256)
void scatter_kernel(const int* __restrict__ ei, int* __restrict__ cursor,
                    int2* __restrict__ csr) {
    int e = blockIdx.x * 256 + threadIdx.x;
    if (e < EE) {
        int src = ei[e], dst = ei[EE + e];
        int pos = atomicAdd(&cursor[dst], 1);
        csr[pos] = make_int2(src, e);
    }
}

// ---------- eatt build: 2 edges/thread, interleaved gathers ----------
__global__ __launch_bounds__(256)
void eatt_build_kernel(const float* __restrict__ edge_attr, const int2* __restrict__ csr,
                       const float* __restrict__ M, __half* __restrict__ eatt) {
    __shared__ float Ms[384];
    for (int i = threadIdx.x; i < 384; i += 256) Ms[i] = M[i];
    __syncthreads();
    int pos0 = (blockIdx.x * 256 + threadIdx.x) * 2;
#pragma unroll
    for (int u = 0; u < 2; ++u) {
        int pos = pos0 + u;
        if (pos >= EE) return;
        int e = csr[pos].y;
        const float4* ep = reinterpret_cast<const float4*>(edge_attr + (size_t)e * 16);
        float4 a0 = ep[0], a1 = ep[1], a2 = ep[2], a3 = ep[3];
        float ea[16] = {a0.x, a0.y, a0.z, a0.w, a1.x, a1.y, a1.z, a1.w,
                        a2.x, a2.y, a2.z, a2.w, a3.x, a3.y, a3.z, a3.w};
#pragma unroll
        for (int l = 0; l < 3; ++l) {
            __half o[8] __attribute__((aligned(16)));
#pragma unroll
            for (int h = 0; h < 8; ++h) {
                const float* mp = Ms + l * 128 + h * 16;
                float acc = 0.f;
#pragma unroll
                for (int d = 0; d < 16; ++d) acc += ea[d] * mp[d];
                o[h] = __float2half(acc);
            }
            *reinterpret_cast<uint4*>(eatt + ((size_t)l * EE + pos) * 8) =
                *reinterpret_cast<const uint4*>(o);
        }
    }
}

// ---------- fused attention: direct-exp softmax, 8/4/1 unroll, fp16 out ----------
__global__ __launch_bounds__(128)
void fused_gat_kernel(const __half* __restrict__ qa, const __half* __restrict__ kv,
                      const __half* __restrict__ eatt_l,
                      const int* __restrict__ offs, const int* __restrict__ deg,
                      const int2* __restrict__ csr, __half* __restrict__ hout) {
    int lane = threadIdx.x & 63;
    int n = blockIdx.x * 2 + (threadIdx.x >> 6);
    if (n >= NN) return;
    int h = lane >> 3;
    int c2h = lane & 7;
    int chh = h * 8 + c2h;

    float2 q = __half22float2(reinterpret_cast<const __half2*>(qa + (size_t)n * 128)[chh]);

    int start = offs[n], d = deg[n];
    const __half* ebase = eatt_l + (size_t)start * 8 + h;
    const int2* cbase = csr + start;

    float den = 0.f, acc0 = 0.f, acc1 = 0.f;
    int i = 0;
    for (; i + 8 <= d; i += 8) {
        int s[8]; float e[8]; __half2 kh[8], vh[8];
#pragma unroll
        for (int j = 0; j < 8; ++j) s[j] = cbase[i + j].x;
#pragma unroll
        for (int j = 0; j < 8; ++j) e[j] = __half2float(ebase[(size_t)(i + j) * 8]);
#pragma unroll
        for (int j = 0; j < 8; ++j) {
            const __half2* ph = reinterpret_cast<const __half2*>(kv + (size_t)s[j] * 256);
            kh[j] = ph[chh];
            vh[j] = ph[64 + chh];
        }
#pragma unroll
        for (int j = 0; j < 8; ++j) {
            float2 k = __half22float2(kh[j]);
            float p = q.x * k.x + q.y * k.y;
            p += __shfl_xor(p, 1); p += __shfl_xor(p, 2); p += __shfl_xor(p, 4);
            float a = p + e[j]; a = a > 0.f ? a : 0.2f * a;
            a = fminf(a, 60.f);
            float w = __expf(a);
            float2 v = __half22float2(vh[j]);
            den += w; acc0 += w * v.x; acc1 += w * v.y;
        }
    }
    for (; i + 4 <= d; i += 4) {
        int s[4]; float e[4]; __half2 kh[4], vh[4];
#pragma unroll
        for (int j = 0; j < 4; ++j) s[j] = cbase[i + j].x;
#pragma unroll
        for (int j = 0; j < 4; ++j) e[j] = __half2float(ebase[(size_t)(i + j) * 8]);
#pragma unroll
        for (int j = 0; j < 4; ++j) {
            const __half2* ph = reinterpret_cast<const __half2*>(kv + (size_t)s[j] * 256);
            kh[j] = ph[chh];
            vh[j] = ph[64 + chh];
        }
#pragma unroll
        for (int j = 0; j < 4; ++j) {
            float2 k = __half22float2(kh[j]);
            float p = q.x * k.x + q.y * k.y;
            p += __shfl_xor(p, 1); p += __shfl_xor(p, 2); p += __shfl_xor(p, 4);
            float a = p + e[j]; a = a > 0.f ? a : 0.2f * a;
            a = fminf(a, 60.f);
            float w = __expf(a);
            float2 v = __half22float2(vh[j]);
            den += w; acc0 += w * v.x; acc1 += w * v.y;
        }
    }
    for (; i < d; ++i) {
        int s0 = cbase[i].x;
        float e0 = __half2float(ebase[(size_t)i * 8]);
        const __half2* ph = reinterpret_cast<const __half2*>(kv + (size_t)s0 * 256);
        float2 k = __half22float2(ph[chh]);
        float2 v = __half22float2(ph[64 + chh]);
        float p = q.x * k.x + q.y * k.y;
        p += __shfl_xor(p, 1); p += __shfl_xor(p, 2); p += __shfl_xor(p, 4);
        float a = p + e0; a = a > 0.f ? a : 0.2f * a;
        a = fminf(a, 60.f);
        float w = __expf(a);
        den += w; acc0 += w * v.x; acc1 += w * v.y;
    }
    float inv = 1.f / (den + 1e-16f);
    reinterpret_cast<__half2*>(hout + (size_t)n * 128)[chh] =
        __float22half2_rn(make_float2(acc0 * inv, acc1 * inv));
}

// ---------- BN stats: 32-row blocks, fp16 input, uint4 loads ----------
__global__ __launch_bounds__(256)
void bn_stats_kernel(const __half* __restrict__ h, float* __restrict__ sums) {
    __shared__ float red[2][16][128];
    int t = threadIdx.x;
    int cg = t & 15;
    int rofs = t >> 4;
    int r0 = blockIdx.x * 32;
    int rend = min(NN, r0 + 32);
    float s1[8], s2[8];
#pragma unroll
    for (int j = 0; j < 8; ++j) { s1[j] = 0.f; s2[j] = 0.f; }
    for (int r = r0 + rofs; r < rend; r += 16) {
        uint4 raw = *reinterpret_cast<const uint4*>(h + (size_t)r * 128 + cg * 8);
        const __half* rh = reinterpret_cast<const __half*>(&raw);
#pragma unroll
        for (int j = 0; j < 8; ++j) {
            float v = __half2float(rh[j]);
            s1[j] += v; s2[j] += v * v;
        }
    }
#pragma unroll
    for (int j = 0; j < 8; ++j) {
        red[0][rofs][cg * 8 + j] = s1[j];
        red[1][rofs][cg * 8 + j] = s2[j];
    }
    __syncthreads();
    if (t < 128) {
        float a = 0.f, b = 0.f;
#pragma unroll
        for (int i = 0; i < 16; ++i) { a += red[0][i][t]; b += red[1][i][t]; }
        unsafeAtomicAdd(&sums[t], a);
        unsafeAtomicAdd(&sums[128 + t], b);
    }
}

// ---------- last layer: BN apply + segmented global max pool (batch sorted) ----------
__global__ __launch_bounds__(256)
void bn_pool_kernel(const __half* __restrict__ h, const float* __restrict__ sums,
                    const float* __restrict__ scale, const float* __restrict__ shift,
                    const int* __restrict__ batch, unsigned* __restrict__ gkey) {
    int t = threadIdx.x;
    int c = t & 127, half = t >> 7;
    int r0 = blockIdx.x * 32;
    int rend = min(NN, r0 + 32);
    const float invN = 1.f / (float)NN;
    float mu = sums[c] * invN;
    float var = sums[128 + c] * invN - mu * mu;
    float iscl = rsqrtf(var + 1e-5f) * scale[c];
    float sh = shift[c];
    int curg = -1;
    float lmax = -INFINITY;
    for (int r = r0 + half; r < rend; r += 2) {
        int g = batch[r];
        if (g != curg) {
            if (curg >= 0) atomicMax(&gkey[curg * 128 + c], f2key(lmax));
            curg = g;
            lmax = -INFINITY;
        }
        float v = (__half2float(h[(size_t)r * 128 + c]) - mu) * iscl + sh;
        lmax = fmaxf(lmax, v);
    }
    if (curg >= 0) atomicMax(&gkey[curg * 128 + c], f2key(lmax));
}

// ---------- head MLP (single block, 256 threads, W1/g staged fp16 in LDS) ----------
__global__ __launch_bounds__(256)
void head_kernel(const unsigned* __restrict__ gkey,
                 const float* __restrict__ W1, const float* __restrict__ b1,
                 const float* __restrict__ bn1s, const float* __restrict__ bn1b,
                 const float* __restrict__ W2, const float* __restrict__ b2,
                 const float* __restrict__ bn2s, const float* __restrict__ bn2b,
                 const float* __restrict__ Wout, const float* __restrict__ bout,
                 float* __restrict__ out) {
    __shared__ __half gh[64][128];     // 16 KB
    __shared__ __half W1s[64][130];    // 16.6 KB (pad 2 to break conflicts)
    __shared__ float z1[64][64];       // 16 KB
    __shared__ float z2[64][32];       // 8 KB
    int t = threadIdx.x;
    for (int i = t; i < 64 * 128; i += 256) gh[i >> 7][i & 127] = __float2half(key2f(gkey[i]));
    for (int i = t; i < 64 * 128; i += 256) W1s[i >> 7][i & 127] = __float2half(W1[i]);
    __syncthreads();
    for (int i = t; i < 64 * 64; i += 256) {
        int r = i >> 6, o = i & 63;
        float acc = b1[o];
#pragma unroll 8
        for (int k2 = 0; k2 < 128; ++k2)
            acc += __half2float(gh[r][k2]) * __half2float(W1s[o][k2]);
        z1[r][o] = acc;
    }
    __syncthreads();
    if (t < 64) {
        float s1 = 0.f, s2 = 0.f;
        for (int r = 0; r < 64; ++r) { float v = z1[r][t]; s1 += v; s2 += v * v; }
        float mu = s1 * (1.f / 64.f), var = s2 * (1.f / 64.f) - mu * mu;
        float inv = rsqrtf(var + 1e-5f) * bn1s[t];
        float sh = bn1b[t];
        for (int r = 0; r < 64; ++r) {
            float v = (z1[r][t] - mu) * inv + sh;
            z1[r][t] = v > 0.f ? v : 0.f;
        }
    }
    __syncthreads();
    for (int i = t; i < 64 * 32; i += 256) {
        int r = i >> 5, o = i & 31;
        const float* wr = W2 + (size_t)o * 64;
        float acc = b2[o];
        for (int k2 = 0; k2 < 64; ++k2) acc += z1[r][k2] * wr[k2];
        z2[r][o] = acc;
    }
    __syncthreads();
    if (t < 32) {
        float s1 = 0.f, s2 = 0.f;
        for (int r = 0; r < 64; ++r) { float v = z2[r][t]; s1 += v; s2 += v * v; }
        float mu = s1 * (1.f / 64.f), var = s2 * (1.f / 64.f) - mu * mu;
        float inv = rsqrtf(var + 1e-5f) * bn2s[t];
        float sh = bn2b[t];
        for (int r = 0; r < 64; ++r) {
            float v = (z2[r][t] - mu) * inv + sh;
            z2[r][t] = v > 0.f ? v : 0.f;
        }
    }
    __syncthreads();
    for (int i = t; i < 64 * 64; i += 256) {
        int r = i >> 6, o = i & 63;
        const float* wr = Wout + (size_t)o * 32;
        float acc = bout[o];
        for (int k2 = 0; k2 < 32; ++k2) acc += z2[r][k2] * wr[k2];
        out[r * 64 + o] = acc;
    }
}

extern "C" void kernel_launch(void* const* d_in, const int* in_sizes, int n_in,
                              void* d_out, int out_size, void* d_ws, size_t ws_size,
                              hipStream_t stream) {
    const float* x         = (const float*)d_in[0];
    const int*   ei        = (const int*)d_in[1];
    const float* edge_attr = (const float*)d_in[2];
    const int*   batch     = (const int*)d_in[3];
    const float* lin_qkv   = (const float*)d_in[4];
    const float* lin_edge  = (const float*)d_in[5];
    const float* att       = (const float*)d_in[6];
    // d_in[7] gat_bias: cancels exactly under training-mode BN (mean-subtracted)
    const float* bn_scale  = (const float*)d_in[8];
    const float* bn_bias   = (const float*)d_in[9];
    const float* W1   = (const float*)d_in[10];
    const float* b1   = (const float*)d_in[11];
    const float* bn1s = (const float*)d_in[12];
    const float* bn1b = (const float*)d_in[13];
    const float* W2   = (const float*)d_in[14];
    const float* b2   = (const float*)d_in[15];
    const float* bn2s = (const float*)d_in[16];
    const float* bn2b = (const float*)d_in[17];
    const float* Wout = (const float*)d_in[18];
    const float* bout = (const float*)d_in[19];

    float* ws = (float*)d_ws;
    size_t off = 0;
    auto alloc = [&](size_t n) { float* p = ws + off; off += n; return p; };
    // contiguous zero-region first: deg | gkey | gsums[3][256]
    int*      deg   = (int*)alloc(NN);
    unsigned* gkey  = (unsigned*)alloc(64 * 128);
    float*    gsums = alloc(3 * 256);
    const size_t zeroBytes = ((size_t)NN + 64 * 128 + 3 * 256) * 4;
    __half* hout = (__half*)alloc((size_t)NN * 64);   // NN*128 halves
    __half* qa   = (__half*)alloc((size_t)NN * 64);
    __half* kv   = (__half*)alloc((size_t)NN * 128);  // k|v interleaved, fp16
    __half* Apack = (__half*)alloc((size_t)MB * 8192);  // MB*16384 halves
    __half* Wpack = (__half*)alloc(9 * 8192);           // 9*16384 halves
    int*    offs   = (int*)alloc(NN);
    int*    cursor = (int*)alloc(NN);
    int2*   csr    = (int2*)alloc((size_t)EE * 2);      // (src, eid)
    __half* eatt   = (__half*)alloc((size_t)3 * EE * 4);  // [l][EE][8] fp16
    int*    psum   = (int*)alloc(256);
    float*  M      = alloc(3 * 128);

    const int edgeBlocks = (EE + 255) / 256;     // 1563
    const int scanBlocks = (NN + 255) / 256;     // 196
    const int packBlocks = MB * 8;               // 3128
    const int statBlocks = (NN + 31) / 32;       // 1563
    const int poolBlocks = (NN + 31) / 32;       // 1563
    const int gatBlocks  = (NN + 1) / 2;         // 25000
    const int eattBlocks = (EE + 511) / 512;     // 782

    hipMemsetAsync(deg, 0, zeroBytes, stream);
    prologue_kernel<<<74 + packBlocks, 256, 0, stream>>>(lin_qkv, lin_edge, att, x, Wpack, M, Apack);
    deg_count_kernel<<<edgeBlocks, 256, 0, stream>>>(ei, deg);
    scan_partial_kernel<<<scanBlocks, 256, 0, stream>>>(deg, psum);
    scan_final_kernel<<<scanBlocks, 256, 0, stream>>>(deg, psum, offs, cursor);
    scatter_kernel<<<edgeBlocks, 256, 0, stream>>>(ei, cursor, csr);
    eatt_build_kernel<<<eattBlocks, 256, 0, stream>>>(edge_attr, csr, M, eatt);

    for (int l = 0; l < 3; ++l) {
        qkv_mfma_kernel<<<MB2, 256, 0, stream>>>(
            Apack, Wpack, l, att + (size_t)l * 384, qa, kv);

        fused_gat_kernel<<<gatBlocks, 128, 0, stream>>>(
            qa, kv, eatt + (size_t)l * EE * 8, offs, deg, csr, hout);

        bn_stats_kernel<<<statBlocks, 256, 0, stream>>>(hout, gsums + l * 256);

        if (l < 2) {
            pack_h_kernel<<<packBlocks, 256, 0, stream>>>(
                hout, gsums + l * 256, bn_scale + l * 128, bn_bias + l * 128, Apack);
        } else {
            bn_pool_kernel<<<poolBlocks, 256, 0, stream>>>(
                hout, gsums + l * 256, bn_scale + l * 128, bn_bias + l * 128, batch, gkey);
        }
    }

    head_kernel<<<1, 256, 0, stream>>>(gkey, W1, b1, bn1s, bn1b, W2, b2, bn2s, bn2b, Wout, bout, (float*)d_out);
}

// Round 14
// 386.420 us; speedup vs baseline: 1.1401x; 1.1401x over previous
//
#include <hip/hip_runtime.h>
#include <hip/hip_bf16.h>
#include <hip/hip_fp16.h>
#include <cstddef>
#include <cstdint>

#define NN 50000
#define EE 400000
#define GG 64
#define MB 391    // ceil(NN/128) (pack granularity)
#define MB2 782   // ceil(NN/64)  (qkv block granularity)

typedef __attribute__((ext_vector_type(8))) _Float16 f16x8;
typedef __attribute__((ext_vector_type(4))) float f32x4;

#define GLOAD_LDS16(g, l) __builtin_amdgcn_global_load_lds( \
    (const __attribute__((address_space(1))) void*)(g), \
    (__attribute__((address_space(3))) void*)(l), 16, 0, 0)

// ---------- helpers ----------
__device__ __forceinline__ unsigned f2key(float f) {
    unsigned u = __float_as_uint(f);
    return (u & 0x80000000u) ? ~u : (u | 0x80000000u);
}
__device__ __forceinline__ float key2f(unsigned k) {
    unsigned u = (k & 0x80000000u) ? (k ^ 0x80000000u) : ~k;
    return __uint_as_float(u);
}

// ---------- M[l][h][d] = sum_c lin_edge[l][h*16+c][d] * att[l][2][h][c] ----------
__global__ void compute_M_kernel(const float* __restrict__ lin_edge,
                                 const float* __restrict__ att,
                                 float* __restrict__ M) {
    int t = blockIdx.x * 256 + threadIdx.x;
    if (t >= 3 * 128) return;
    int l = t >> 7, r = t & 127, h = r >> 4, d = r & 15;
    const float* le = lin_edge + (size_t)l * 128 * 16;
    const float* av = att + ((l * 3 + 2) * 128) + h * 16;
    float acc = 0.f;
#pragma unroll
    for (int c = 0; c < 16; ++c) acc += le[(h * 16 + c) * 16 + d] * av[c];
    M[t] = acc;
}

// ---------- weight packing (fp16): Wpack[l*3+mat][kb 4][kg 4][n 128][8k] ----------
__global__ __launch_bounds__(256)
void wpack_kernel(const float* __restrict__ lin_qkv, __half* __restrict__ Wpack) {
    int g = blockIdx.x * 256 + threadIdx.x;   // [0, 9*2048)
    int lm = g >> 11;
    int r = g & 2047;
    int kb = r >> 9;
    int kg = (r >> 7) & 3;
    int n  = r & 127;
    int k0 = kb * 32 + kg * 8;
    const float* row = lin_qkv + ((size_t)lm * 128 + n) * 128 + k0;
    __half o[8] __attribute__((aligned(16)));
#pragma unroll
    for (int i = 0; i < 8; ++i) o[i] = __float2half(row[i]);
    *reinterpret_cast<uint4*>(Wpack + (size_t)g * 8) = *reinterpret_cast<const uint4*>(o);
}

// ---------- x packing (fp32 in, no BN): Apack[mb][kb 4][kg 4][m 128][8k] ----------
__global__ __launch_bounds__(256)
void pack_x_kernel(const float* __restrict__ hin, __half* __restrict__ Apack) {
    int s = blockIdx.x * 256 + threadIdx.x;   // [0, MB*2048)
    int mb = s >> 11;
    int r  = s & 2047;
    int kb = r >> 9;
    int kg = (r >> 7) & 3;
    int m  = r & 127;
    int node = mb * 128 + m;
    int k0 = kb * 32 + kg * 8;
    size_t slot = ((size_t)(mb * 4 + kb) * 512 + (size_t)kg * 128 + m) * 8;
    __half o[8] __attribute__((aligned(16)));
    if (node < NN) {
        const float* row = hin + (size_t)node * 128 + k0;
#pragma unroll
        for (int i = 0; i < 8; ++i) o[i] = __float2half(row[i]);
    } else {
#pragma unroll
        for (int i = 0; i < 8; ++i) o[i] = __float2half(0.f);
    }
    *reinterpret_cast<uint4*>(Apack + slot) = *reinterpret_cast<const uint4*>(o);
}

// ---------- h packing (fp16 in, BN+relu): Apack[mb][kb 4][kg 4][m 128][8k] ----------
__global__ __launch_bounds__(256)
void pack_h_kernel(const __half* __restrict__ hin, const float* __restrict__ sums,
                   const float* __restrict__ scale, const float* __restrict__ shift,
                   __half* __restrict__ Apack) {
    int s = blockIdx.x * 256 + threadIdx.x;   // [0, MB*2048)
    int mb = s >> 11;
    int r  = s & 2047;
    int kb = r >> 9;
    int kg = (r >> 7) & 3;
    int m  = r & 127;
    int node = mb * 128 + m;
    int k0 = kb * 32 + kg * 8;
    size_t slot = ((size_t)(mb * 4 + kb) * 512 + (size_t)kg * 128 + m) * 8;
    __half o[8] __attribute__((aligned(16)));
    if (node < NN) {
        const __half* row = hin + (size_t)node * 128 + k0;
        uint4 raw = *reinterpret_cast<const uint4*>(row);
        const __half* rh = reinterpret_cast<const __half*>(&raw);
#pragma unroll
        for (int i = 0; i < 8; ++i) {
            int c = k0 + i;
            float mu = sums[c] * (1.f / NN);
            float var = sums[128 + c] * (1.f / NN) - mu * mu;
            float v = (__half2float(rh[i]) - mu) * rsqrtf(var + 1e-5f) * scale[c] + shift[c];
            v = v > 0.f ? v : 0.f;
            o[i] = __float2half(v);
        }
    } else {
#pragma unroll
        for (int i = 0; i < 8; ++i) o[i] = __float2half(0.f);
    }
    *reinterpret_cast<uint4*>(Apack + slot) = *reinterpret_cast<const uint4*>(o);
}

// ---------- merged QKV GEMM: 64-row blocks, A staged once, all 3 mats ----------
__global__ __launch_bounds__(256, 4)
void qkv_mfma_kernel(const __half* __restrict__ Apack,
                     const __half* __restrict__ Wpack,
                     int layer,
                     const float* __restrict__ att_l,
                     __half* __restrict__ qa, __half* __restrict__ kv) {
    __shared__ __half As[4][2048];
    __shared__ __half Bb[2][4096];
    const int t = threadIdx.x;
    const int lane = t & 63;
    const int wave = t >> 6;
    const int wr = wave >> 1, wc = wave & 1;
    const int r0 = blockIdx.x * 64;
    const int mbk = blockIdx.x >> 1;
    const int half = blockIdx.x & 1;

    const __half* Abase = Apack + (size_t)mbk * 16384;
    const __half* Bl = Wpack + (size_t)layer * 3 * 16384;

#pragma unroll
    for (int kb = 0; kb < 4; ++kb) {
        const __half* ga = Abase + (size_t)kb * 4096 + (size_t)(t >> 6) * 1024 + half * 512 + (size_t)(t & 63) * 8;
        GLOAD_LDS16(ga, &As[kb][((t >> 6) * 64 + (t & 63)) * 8]);
    }
    {
        const __half* gb = Bl + (size_t)t * 8;
        GLOAD_LDS16(gb, &Bb[0][(size_t)t * 8]);
        GLOAD_LDS16(gb + 2048, &Bb[0][2048 + (size_t)t * 8]);
    }
    __syncthreads();

    const int abase = ((lane >> 4) * 64 + wr * 32 + (lane & 15)) * 8;
    const int bbase = ((lane >> 4) * 128 + wc * 64 + (lane & 15)) * 8;
    const int rowq = (lane >> 4) * 4;

    for (int mat = 0; mat < 3; ++mat) {
        f32x4 acc[2][4];
#pragma unroll
        for (int i = 0; i < 2; ++i)
#pragma unroll
            for (int j = 0; j < 4; ++j) acc[i][j] = (f32x4){0.f, 0.f, 0.f, 0.f};

#pragma unroll
        for (int c = 0; c < 4; ++c) {
            int g = mat * 4 + c;
            if (g < 11) {
                const __half* gb = Bl + (size_t)(g + 1) * 4096 + (size_t)t * 8;
                GLOAD_LDS16(gb, &Bb[(g + 1) & 1][(size_t)t * 8]);
                GLOAD_LDS16(gb + 2048, &Bb[(g + 1) & 1][2048 + (size_t)t * 8]);
            }
            f16x8 aF[2], bF[4];
#pragma unroll
            for (int mf = 0; mf < 2; ++mf)
                aF[mf] = *reinterpret_cast<const f16x8*>(&As[c][abase + mf * 128]);
#pragma unroll
            for (int nf = 0; nf < 4; ++nf)
                bF[nf] = *reinterpret_cast<const f16x8*>(&Bb[g & 1][bbase + nf * 128]);
#pragma unroll
            for (int mf = 0; mf < 2; ++mf)
#pragma unroll
                for (int nf = 0; nf < 4; ++nf)
                    acc[mf][nf] = __builtin_amdgcn_mfma_f32_16x16x32_f16(aF[mf], bF[nf], acc[mf][nf], 0, 0, 0);
            __syncthreads();
        }

        __half* outb = (mat == 0) ? qa : kv;
        const size_t stride = (mat == 0) ? 128 : 256;
        const int coloff = (mat == 2) ? 128 : 0;
        float sc[4];
#pragma unroll
        for (int nf = 0; nf < 4; ++nf) {
            int col = wc * 64 + nf * 16 + (lane & 15);
            sc[nf] = (mat == 2) ? 1.f : att_l[mat * 128 + col];
        }
#pragma unroll
        for (int mf = 0; mf < 2; ++mf) {
            int row0 = r0 + wr * 32 + mf * 16 + rowq;
#pragma unroll
            for (int reg = 0; reg < 4; ++reg) {
                int row = row0 + reg;
                if (row < NN) {
#pragma unroll
                    for (int nf = 0; nf < 4; ++nf) {
                        int col = wc * 64 + nf * 16 + (lane & 15);
                        outb[(size_t)row * stride + coloff + col] = __float2half(acc[mf][nf][reg] * sc[nf]);
                    }
                }
            }
        }
    }
}

// ---------- CSR build ----------
__global__ __launch_bounds__(256)
void deg_count_kernel(const int* __restrict__ ei, int* __restrict__ deg) {
    int e = blockIdx.x * 256 + threadIdx.x;
    if (e < EE) atomicAdd(&deg[ei[EE + e]], 1);
}

__global__ __launch_bounds__(256)
void scan_partial_kernel(const int* __restrict__ deg, int* __restrict__ psum) {
    __shared__ int red[256];
    int i = blockIdx.x * 256 + threadIdx.x;
    red[threadIdx.x] = (i < NN) ? deg[i] : 0;
    __syncthreads();
    for (int o = 128; o > 0; o >>= 1) {
        if (threadIdx.x < o) red[threadIdx.x] += red[threadIdx.x + o];
        __syncthreads();
    }
    if (threadIdx.x == 0) psum[blockIdx.x] = red[0];
}

// scan_final with fused top-level prefix: block b sums psum[0..b) itself
__global__ __launch_bounds__(256)
void scan_final_kernel(const int* __restrict__ deg, const int* __restrict__ psum,
                       int* __restrict__ offs, int* __restrict__ cursor) {
    __shared__ int red[256];
    __shared__ int sh[256];
    int t = threadIdx.x;
    int b = blockIdx.x;
    red[t] = (t < b) ? psum[t] : 0;   // b <= 195 < 196 entries
    __syncthreads();
    for (int o = 128; o > 0; o >>= 1) {
        if (t < o) red[t] += red[t + o];
        __syncthreads();
    }
    int base = red[0];
    int i = b * 256 + t;
    int v = (i < NN) ? deg[i] : 0;
    sh[t] = v;
    __syncthreads();
    for (int o = 1; o < 256; o <<= 1) {
        int add = (t >= o) ? sh[t - o] : 0;
        __syncthreads();
        sh[t] += add;
        __syncthreads();
    }
    if (i < NN) {
        int excl = sh[t] - v + base;
        offs[i] = excl;
        cursor[i] = excl;
    }
}

// ---------- scatter: single 8B store per edge ----------
__global__ __launch_bounds__(256)
void scatter_kernel(const int* __restrict__ ei, int* __restrict__ cursor,
                    int2* __restrict__ csr) {
    int e = blockIdx.x * 256 + threadIdx.x;
    if (e < EE) {
        int src = ei[e], dst = ei[EE + e];
        int pos = atomicAdd(&cursor[dst], 1);
        csr[pos] = make_int2(src, e);
    }
}

// ---------- eatt build: sequential pos (1 edge/thread), coalesced writes ----------
__global__ __launch_bounds__(256)
void eatt_build_kernel(const float* __restrict__ edge_attr, const int2* __restrict__ csr,
                       const float* __restrict__ M, __half* __restrict__ eatt) {
    __shared__ float Ms[384];
    for (int i = threadIdx.x; i < 384; i += 256) Ms[i] = M[i];
    __syncthreads();
    int pos = blockIdx.x * 256 + threadIdx.x;
    if (pos >= EE) return;
    int e = csr[pos].y;
    const float4* ep = reinterpret_cast<const float4*>(edge_attr + (size_t)e * 16);
    float4 a0 = ep[0], a1 = ep[1], a2 = ep[2], a3 = ep[3];
    float ea[16] = {a0.x, a0.y, a0.z, a0.w, a1.x, a1.y, a1.z, a1.w,
                    a2.x, a2.y, a2.z, a2.w, a3.x, a3.y, a3.z, a3.w};
#pragma unroll
    for (int l = 0; l < 3; ++l) {
        __half o[8] __attribute__((aligned(16)));
#pragma unroll
        for (int h = 0; h < 8; ++h) {
            const float* mp = Ms + l * 128 + h * 16;
            float acc = 0.f;
#pragma unroll
            for (int d = 0; d < 16; ++d) acc += ea[d] * mp[d];
            o[h] = __float2half(acc);
        }
        *reinterpret_cast<uint4*>(eatt + ((size_t)l * EE + pos) * 8) =
            *reinterpret_cast<const uint4*>(o);
    }
}

// ---------- fused attention: direct-exp softmax, 8/4/1 unroll, fp16 out ----------
__global__ __launch_bounds__(128)
void fused_gat_kernel(const __half* __restrict__ qa, const __half* __restrict__ kv,
                      const __half* __restrict__ eatt_l,
                      const int* __restrict__ offs, const int* __restrict__ deg,
                      const int2* __restrict__ csr, __half* __restrict__ hout) {
    int lane = threadIdx.x & 63;
    int n = blockIdx.x * 2 + (threadIdx.x >> 6);
    if (n >= NN) return;
    int h = lane >> 3;
    int c2h = lane & 7;
    int chh = h * 8 + c2h;

    float2 q = __half22float2(reinterpret_cast<const __half2*>(qa + (size_t)n * 128)[chh]);

    int start = offs[n], d = deg[n];
    const __half* ebase = eatt_l + (size_t)start * 8 + h;
    const int2* cbase = csr + start;

    float den = 0.f, acc0 = 0.f, acc1 = 0.f;
    int i = 0;
    for (; i + 8 <= d; i += 8) {
        int s[8]; float e[8]; __half2 kh[8], vh[8];
#pragma unroll
        for (int j = 0; j < 8; ++j) s[j] = cbase[i + j].x;
#pragma unroll
        for (int j = 0; j < 8; ++j) e[j] = __half2float(ebase[(size_t)(i + j) * 8]);
#pragma unroll
        for (int j = 0; j < 8; ++j) {
            const __half2* ph = reinterpret_cast<const __half2*>(kv + (size_t)s[j] * 256);
            kh[j] = ph[chh];
            vh[j] = ph[64 + chh];
        }
#pragma unroll
        for (int j = 0; j < 8; ++j) {
            float2 k = __half22float2(kh[j]);
            float p = q.x * k.x + q.y * k.y;
            p += __shfl_xor(p, 1); p += __shfl_xor(p, 2); p += __shfl_xor(p, 4);
            float a = p + e[j]; a = a > 0.f ? a : 0.2f * a;
            a = fminf(a, 60.f);
            float w = __expf(a);
            float2 v = __half22float2(vh[j]);
            den += w; acc0 += w * v.x; acc1 += w * v.y;
        }
    }
    for (; i + 4 <= d; i += 4) {
        int s[4]; float e[4]; __half2 kh[4], vh[4];
#pragma unroll
        for (int j = 0; j < 4; ++j) s[j] = cbase[i + j].x;
#pragma unroll
        for (int j = 0; j < 4; ++j) e[j] = __half2float(ebase[(size_t)(i + j) * 8]);
#pragma unroll
        for (int j = 0; j < 4; ++j) {
            const __half2* ph = reinterpret_cast<const __half2*>(kv + (size_t)s[j] * 256);
            kh[j] = ph[chh];
            vh[j] = ph[64 + chh];
        }
#pragma unroll
        for (int j = 0; j < 4; ++j) {
            float2 k = __half22float2(kh[j]);
            float p = q.x * k.x + q.y * k.y;
            p += __shfl_xor(p, 1); p += __shfl_xor(p, 2); p += __shfl_xor(p, 4);
            float a = p + e[j]; a = a > 0.f ? a : 0.2f * a;
            a = fminf(a, 60.f);
            float w = __expf(a);
            float2 v = __half22float2(vh[j]);
            den += w; acc0 += w * v.x; acc1 += w * v.y;
        }
    }
    for (; i < d; ++i) {
        int s0 = cbase[i].x;
        float e0 = __half2float(ebase[(size_t)i * 8]);
        const __half2* ph = reinterpret_cast<const __half2*>(kv + (size_t)s0 * 256);
        float2 k = __half22float2(ph[chh]);
        float2 v = __half22float2(ph[64 + chh]);
        float p = q.x * k.x + q.y * k.y;
        p += __shfl_xor(p, 1); p += __shfl_xor(p, 2); p += __shfl_xor(p, 4);
        float a = p + e0; a = a > 0.f ? a : 0.2f * a;
        a = fminf(a, 60.f);
        float w = __expf(a);
        den += w; acc0 += w * v.x; acc1 += w * v.y;
    }
    float inv = 1.f / (den + 1e-16f);
    reinterpret_cast<__half2*>(hout + (size_t)n * 128)[chh] =
        __float22half2_rn(make_float2(acc0 * inv, acc1 * inv));
}

// ---------- BN stats (sum, sumsq per channel), fp16 input, uint4 loads ----------
__global__ __launch_bounds__(256)
void bn_stats_kernel(const __half* __restrict__ h, float* __restrict__ sums) {
    __shared__ float red[2][16][128];
    int t = threadIdx.x;
    int cg = t & 15;
    int rofs = t >> 4;
    int r0 = blockIdx.x * 64;
    int rend = min(NN, r0 + 64);
    float s1[8], s2[8];
#pragma unroll
    for (int j = 0; j < 8; ++j) { s1[j] = 0.f; s2[j] = 0.f; }
    for (int r = r0 + rofs; r < rend; r += 16) {
        uint4 raw = *reinterpret_cast<const uint4*>(h + (size_t)r * 128 + cg * 8);
        const __half* rh = reinterpret_cast<const __half*>(&raw);
#pragma unroll
        for (int j = 0; j < 8; ++j) {
            float v = __half2float(rh[j]);
            s1[j] += v; s2[j] += v * v;
        }
    }
#pragma unroll
    for (int j = 0; j < 8; ++j) {
        red[0][rofs][cg * 8 + j] = s1[j];
        red[1][rofs][cg * 8 + j] = s2[j];
    }
    __syncthreads();
    if (t < 128) {
        float a = 0.f, b = 0.f;
#pragma unroll
        for (int i = 0; i < 16; ++i) { a += red[0][i][t]; b += red[1][i][t]; }
        unsafeAtomicAdd(&sums[t], a);
        unsafeAtomicAdd(&sums[128 + t], b);
    }
}

// ---------- last layer: BN apply + segmented global max pool (batch sorted) ----------
__global__ __launch_bounds__(256)
void bn_pool_kernel(const __half* __restrict__ h, const float* __restrict__ sums,
                    const float* __restrict__ scale, const float* __restrict__ shift,
                    const int* __restrict__ batch, unsigned* __restrict__ gkey) {
    int t = threadIdx.x;
    int c = t & 127, half = t >> 7;
    int r0 = blockIdx.x * 32;
    int rend = min(NN, r0 + 32);
    const float invN = 1.f / (float)NN;
    float mu = sums[c] * invN;
    float var = sums[128 + c] * invN - mu * mu;
    float iscl = rsqrtf(var + 1e-5f) * scale[c];
    float sh = shift[c];
    int curg = -1;
    float lmax = -INFINITY;
    for (int r = r0 + half; r < rend; r += 2) {
        int g = batch[r];
        if (g != curg) {
            if (curg >= 0) atomicMax(&gkey[curg * 128 + c], f2key(lmax));
            curg = g;
            lmax = -INFINITY;
        }
        float v = (__half2float(h[(size_t)r * 128 + c]) - mu) * iscl + sh;
        lmax = fmaxf(lmax, v);
    }
    if (curg >= 0) atomicMax(&gkey[curg * 128 + c], f2key(lmax));
}

// ---------- head MLP (single block, 256 threads) ----------
__global__ __launch_bounds__(256)
void head_kernel(const unsigned* __restrict__ gkey,
                 const float* __restrict__ W1, const float* __restrict__ b1,
                 const float* __restrict__ bn1s, const float* __restrict__ bn1b,
                 const float* __restrict__ W2, const float* __restrict__ b2,
                 const float* __restrict__ bn2s, const float* __restrict__ bn2b,
                 const float* __restrict__ Wout, const float* __restrict__ bout,
                 float* __restrict__ out) {
    __shared__ float g[64][128];
    __shared__ float z1[64][64];
    __shared__ float z2[64][32];
    int t = threadIdx.x;
    for (int i = t; i < 64 * 128; i += 256) g[i >> 7][i & 127] = key2f(gkey[i]);
    __syncthreads();
    for (int i = t; i < 64 * 64; i += 256) {
        int r = i >> 6, o = i & 63;
        const float* gr = g[r];
        const float* wr = W1 + (size_t)o * 128;
        float acc = b1[o];
        for (int k2 = 0; k2 < 128; ++k2) acc += gr[k2] * wr[k2];
        z1[r][o] = acc;
    }
    __syncthreads();
    if (t < 64) {
        float s1 = 0.f, s2 = 0.f;
        for (int r = 0; r < 64; ++r) { float v = z1[r][t]; s1 += v; s2 += v * v; }
        float mu = s1 * (1.f / 64.f), var = s2 * (1.f / 64.f) - mu * mu;
        float inv = rsqrtf(var + 1e-5f) * bn1s[t];
        float sh = bn1b[t];
        for (int r = 0; r < 64; ++r) {
            float v = (z1[r][t] - mu) * inv + sh;
            z1[r][t] = v > 0.f ? v : 0.f;
        }
    }
    __syncthreads();
    for (int i = t; i < 64 * 32; i += 256) {
        int r = i >> 5, o = i & 31;
        const float* wr = W2 + (size_t)o * 64;
        float acc = b2[o];
        for (int k2 = 0; k2 < 64; ++k2) acc += z1[r][k2] * wr[k2];
        z2[r][o] = acc;
    }
    __syncthreads();
    if (t < 32) {
        float s1 = 0.f, s2 = 0.f;
        for (int r = 0; r < 64; ++r) { float v = z2[r][t]; s1 += v; s2 += v * v; }
        float mu = s1 * (1.f / 64.f), var = s2 * (1.f / 64.f) - mu * mu;
        float inv = rsqrtf(var + 1e-5f) * bn2s[t];
        float sh = bn2b[t];
        for (int r = 0; r < 64; ++r) {
            float v = (z2[r][t] - mu) * inv + sh;
            z2[r][t] = v > 0.f ? v : 0.f;
        }
    }
    __syncthreads();
    for (int i = t; i < 64 * 64; i += 256) {
        int r = i >> 6, o = i & 63;
        const float* wr = Wout + (size_t)o * 32;
        float acc = bout[o];
        for (int k2 = 0; k2 < 32; ++k2) acc += z2[r][k2] * wr[k2];
        out[r * 64 + o] = acc;
    }
}

extern "C" void kernel_launch(void* const* d_in, const int* in_sizes, int n_in,
                              void* d_out, int out_size, void* d_ws, size_t ws_size,
                              hipStream_t stream) {
    const float* x         = (const float*)d_in[0];
    const int*   ei        = (const int*)d_in[1];
    const float* edge_attr = (const float*)d_in[2];
    const int*   batch     = (const int*)d_in[3];
    const float* lin_qkv   = (const float*)d_in[4];
    const float* lin_edge  = (const float*)d_in[5];
    const float* att       = (const float*)d_in[6];
    // d_in[7] gat_bias: cancels exactly under training-mode BN (mean-subtracted)
    const float* bn_scale  = (const float*)d_in[8];
    const float* bn_bias   = (const float*)d_in[9];
    const float* W1   = (const float*)d_in[10];
    const float* b1   = (const float*)d_in[11];
    const float* bn1s = (const float*)d_in[12];
    const float* bn1b = (const float*)d_in[13];
    const float* W2   = (const float*)d_in[14];
    const float* b2   = (const float*)d_in[15];
    const float* bn2s = (const float*)d_in[16];
    const float* bn2b = (const float*)d_in[17];
    const float* Wout = (const float*)d_in[18];
    const float* bout = (const float*)d_in[19];

    float* ws = (float*)d_ws;
    size_t off = 0;
    auto alloc = [&](size_t n) { float* p = ws + off; off += n; return p; };
    // contiguous zero-region first: deg | gkey | gsums[3][256]
    int*      deg   = (int*)alloc(NN);
    unsigned* gkey  = (unsigned*)alloc(64 * 128);
    float*    gsums = alloc(3 * 256);
    const size_t zeroBytes = ((size_t)NN + 64 * 128 + 3 * 256) * 4;
    __half* hout = (__half*)alloc((size_t)NN * 64);   // NN*128 halves
    __half* qa   = (__half*)alloc((size_t)NN * 64);
    __half* kv   = (__half*)alloc((size_t)NN * 128);  // k|v interleaved, fp16
    __half* Apack = (__half*)alloc((size_t)MB * 8192);  // MB*16384 halves
    __half* Wpack = (__half*)alloc(9 * 8192);           // 9*16384 halves
    int*    offs   = (int*)alloc(NN);
    int*    cursor = (int*)alloc(NN);
    int2*   csr    = (int2*)alloc((size_t)EE * 2);      // (src, eid)
    __half* eatt   = (__half*)alloc((size_t)3 * EE * 4);  // [l][EE][8] fp16
    int*    psum   = (int*)alloc(256);
    float*  M      = alloc(3 * 128);

    const int edgeBlocks = (EE + 255) / 256;     // 1563
    const int scanBlocks = (NN + 255) / 256;     // 196
    const int packBlocks = MB * 8;               // 3128
    const int statBlocks = (NN + 63) / 64;       // 782
    const int poolBlocks = (NN + 31) / 32;       // 1563
    const int gatBlocks  = (NN + 1) / 2;         // 25000

    hipMemsetAsync(deg, 0, zeroBytes, stream);
    wpack_kernel<<<72, 256, 0, stream>>>(lin_qkv, Wpack);
    compute_M_kernel<<<2, 256, 0, stream>>>(lin_edge, att, M);
    deg_count_kernel<<<edgeBlocks, 256, 0, stream>>>(ei, deg);
    scan_partial_kernel<<<scanBlocks, 256, 0, stream>>>(deg, psum);
    scan_final_kernel<<<scanBlocks, 256, 0, stream>>>(deg, psum, offs, cursor);
    scatter_kernel<<<edgeBlocks, 256, 0, stream>>>(ei, cursor, csr);
    eatt_build_kernel<<<edgeBlocks, 256, 0, stream>>>(edge_attr, csr, M, eatt);
    pack_x_kernel<<<packBlocks, 256, 0, stream>>>(x, Apack);

    for (int l = 0; l < 3; ++l) {
        qkv_mfma_kernel<<<MB2, 256, 0, stream>>>(
            Apack, Wpack, l, att + (size_t)l * 384, qa, kv);

        fused_gat_kernel<<<gatBlocks, 128, 0, stream>>>(
            qa, kv, eatt + (size_t)l * EE * 8, offs, deg, csr, hout);

        bn_stats_kernel<<<statBlocks, 256, 0, stream>>>(hout, gsums + l * 256);

        if (l < 2) {
            pack_h_kernel<<<packBlocks, 256, 0, stream>>>(
                hout, gsums + l * 256, bn_scale + l * 128, bn_bias + l * 128, Apack);
        } else {
            bn_pool_kernel<<<poolBlocks, 256, 0, stream>>>(
                hout, gsums + l * 256, bn_scale + l * 128, bn_bias + l * 128, batch, gkey);
        }
    }

    head_kernel<<<1, 256, 0, stream>>>(gkey, W1, b1, bn1s, bn1b, W2, b2, bn2s, bn2b, Wout, bout, (float*)d_out);
}

// Round 15
// 386.088 us; speedup vs baseline: 1.1411x; 1.0009x over previous
//
#include <hip/hip_runtime.h>
#include <hip/hip_bf16.h>
#include <hip/hip_fp16.h>
#include <hip/hip_fp8.h>
#include <cstddef>
#include <cstdint>

#define NN 50000
#define EE 400000
#define GG 64
#define MB 391    // ceil(NN/128) (pack granularity)
#define MB2 782   // ceil(NN/64)  (qkv block granularity)

typedef __attribute__((ext_vector_type(8))) _Float16 f16x8;
typedef __attribute__((ext_vector_type(4))) float f32x4;

#define GLOAD_LDS16(g, l) __builtin_amdgcn_global_load_lds( \
    (const __attribute__((address_space(1))) void*)(g), \
    (__attribute__((address_space(3))) void*)(l), 16, 0, 0)

// ---------- helpers ----------
__device__ __forceinline__ unsigned f2key(float f) {
    unsigned u = __float_as_uint(f);
    return (u & 0x80000000u) ? ~u : (u | 0x80000000u);
}
__device__ __forceinline__ float key2f(unsigned k) {
    unsigned u = (k & 0x80000000u) ? (k ^ 0x80000000u) : ~k;
    return __uint_as_float(u);
}
__device__ __forceinline__ unsigned char f2e4m3(float f) {
    __hip_fp8_e4m3 t(f);
    return (unsigned char)t.__x;
}
__device__ __forceinline__ float e4m32f(unsigned char b) {
    __hip_fp8_e4m3 t;
    t.__x = (__hip_fp8_storage_t)b;
    return (float)t;
}

// ---------- M[l][h][d] = sum_c lin_edge[l][h*16+c][d] * att[l][2][h][c] ----------
__global__ void compute_M_kernel(const float* __restrict__ lin_edge,
                                 const float* __restrict__ att,
                                 float* __restrict__ M) {
    int t = blockIdx.x * 256 + threadIdx.x;
    if (t >= 3 * 128) return;
    int l = t >> 7, r = t & 127, h = r >> 4, d = r & 15;
    const float* le = lin_edge + (size_t)l * 128 * 16;
    const float* av = att + ((l * 3 + 2) * 128) + h * 16;
    float acc = 0.f;
#pragma unroll
    for (int c = 0; c < 16; ++c) acc += le[(h * 16 + c) * 16 + d] * av[c];
    M[t] = acc;
}

// ---------- weight packing (fp16): Wpack[l*3+mat][kb 4][kg 4][n 128][8k] ----------
__global__ __launch_bounds__(256)
void wpack_kernel(const float* __restrict__ lin_qkv, __half* __restrict__ Wpack) {
    int g = blockIdx.x * 256 + threadIdx.x;   // [0, 9*2048)
    int lm = g >> 11;
    int r = g & 2047;
    int kb = r >> 9;
    int kg = (r >> 7) & 3;
    int n  = r & 127;
    int k0 = kb * 32 + kg * 8;
    const float* row = lin_qkv + ((size_t)lm * 128 + n) * 128 + k0;
    __half o[8] __attribute__((aligned(16)));
#pragma unroll
    for (int i = 0; i < 8; ++i) o[i] = __float2half(row[i]);
    *reinterpret_cast<uint4*>(Wpack + (size_t)g * 8) = *reinterpret_cast<const uint4*>(o);
}

// ---------- x packing (fp32 in, no BN): Apack[mb][kb 4][kg 4][m 128][8k] ----------
__global__ __launch_bounds__(256)
void pack_x_kernel(const float* __restrict__ hin, __half* __restrict__ Apack) {
    int s = blockIdx.x * 256 + threadIdx.x;   // [0, MB*2048)
    int mb = s >> 11;
    int r  = s & 2047;
    int kb = r >> 9;
    int kg = (r >> 7) & 3;
    int m  = r & 127;
    int node = mb * 128 + m;
    int k0 = kb * 32 + kg * 8;
    size_t slot = ((size_t)(mb * 4 + kb) * 512 + (size_t)kg * 128 + m) * 8;
    __half o[8] __attribute__((aligned(16)));
    if (node < NN) {
        const float* row = hin + (size_t)node * 128 + k0;
#pragma unroll
        for (int i = 0; i < 8; ++i) o[i] = __float2half(row[i]);
    } else {
#pragma unroll
        for (int i = 0; i < 8; ++i) o[i] = __float2half(0.f);
    }
    *reinterpret_cast<uint4*>(Apack + slot) = *reinterpret_cast<const uint4*>(o);
}

// ---------- h packing (fp16 in, BN+relu): Apack[mb][kb 4][kg 4][m 128][8k] ----------
__global__ __launch_bounds__(256)
void pack_h_kernel(const __half* __restrict__ hin, const float* __restrict__ sums,
                   const float* __restrict__ scale, const float* __restrict__ shift,
                   __half* __restrict__ Apack) {
    int s = blockIdx.x * 256 + threadIdx.x;   // [0, MB*2048)
    int mb = s >> 11;
    int r  = s & 2047;
    int kb = r >> 9;
    int kg = (r >> 7) & 3;
    int m  = r & 127;
    int node = mb * 128 + m;
    int k0 = kb * 32 + kg * 8;
    size_t slot = ((size_t)(mb * 4 + kb) * 512 + (size_t)kg * 128 + m) * 8;
    __half o[8] __attribute__((aligned(16)));
    if (node < NN) {
        const __half* row = hin + (size_t)node * 128 + k0;
        uint4 raw = *reinterpret_cast<const uint4*>(row);
        const __half* rh = reinterpret_cast<const __half*>(&raw);
#pragma unroll
        for (int i = 0; i < 8; ++i) {
            int c = k0 + i;
            float mu = sums[c] * (1.f / NN);
            float var = sums[128 + c] * (1.f / NN) - mu * mu;
            float v = (__half2float(rh[i]) - mu) * rsqrtf(var + 1e-5f) * scale[c] + shift[c];
            v = v > 0.f ? v : 0.f;
            o[i] = __float2half(v);
        }
    } else {
#pragma unroll
        for (int i = 0; i < 8; ++i) o[i] = __float2half(0.f);
    }
    *reinterpret_cast<uint4*>(Apack + slot) = *reinterpret_cast<const uint4*>(o);
}

// ---------- merged QKV GEMM: 64-row blocks, A staged once, all 3 mats ----------
// q -> qa[n][128] fp16; k -> kv row bytes [0,128) fp8; v -> kv row bytes [128,384) fp16
__global__ __launch_bounds__(256, 4)
void qkv_mfma_kernel(const __half* __restrict__ Apack,
                     const __half* __restrict__ Wpack,
                     int layer,
                     const float* __restrict__ att_l,
                     __half* __restrict__ qa, unsigned char* __restrict__ kvb) {
    __shared__ __half As[4][2048];
    __shared__ __half Bb[2][4096];
    const int t = threadIdx.x;
    const int lane = t & 63;
    const int wave = t >> 6;
    const int wr = wave >> 1, wc = wave & 1;
    const int r0 = blockIdx.x * 64;
    const int mbk = blockIdx.x >> 1;
    const int half = blockIdx.x & 1;

    const __half* Abase = Apack + (size_t)mbk * 16384;
    const __half* Bl = Wpack + (size_t)layer * 3 * 16384;

#pragma unroll
    for (int kb = 0; kb < 4; ++kb) {
        const __half* ga = Abase + (size_t)kb * 4096 + (size_t)(t >> 6) * 1024 + half * 512 + (size_t)(t & 63) * 8;
        GLOAD_LDS16(ga, &As[kb][((t >> 6) * 64 + (t & 63)) * 8]);
    }
    {
        const __half* gb = Bl + (size_t)t * 8;
        GLOAD_LDS16(gb, &Bb[0][(size_t)t * 8]);
        GLOAD_LDS16(gb + 2048, &Bb[0][2048 + (size_t)t * 8]);
    }
    __syncthreads();

    const int abase = ((lane >> 4) * 64 + wr * 32 + (lane & 15)) * 8;
    const int bbase = ((lane >> 4) * 128 + wc * 64 + (lane & 15)) * 8;
    const int rowq = (lane >> 4) * 4;

    for (int mat = 0; mat < 3; ++mat) {
        f32x4 acc[2][4];
#pragma unroll
        for (int i = 0; i < 2; ++i)
#pragma unroll
            for (int j = 0; j < 4; ++j) acc[i][j] = (f32x4){0.f, 0.f, 0.f, 0.f};

#pragma unroll
        for (int c = 0; c < 4; ++c) {
            int g = mat * 4 + c;
            if (g < 11) {
                const __half* gb = Bl + (size_t)(g + 1) * 4096 + (size_t)t * 8;
                GLOAD_LDS16(gb, &Bb[(g + 1) & 1][(size_t)t * 8]);
                GLOAD_LDS16(gb + 2048, &Bb[(g + 1) & 1][2048 + (size_t)t * 8]);
            }
            f16x8 aF[2], bF[4];
#pragma unroll
            for (int mf = 0; mf < 2; ++mf)
                aF[mf] = *reinterpret_cast<const f16x8*>(&As[c][abase + mf * 128]);
#pragma unroll
            for (int nf = 0; nf < 4; ++nf)
                bF[nf] = *reinterpret_cast<const f16x8*>(&Bb[g & 1][bbase + nf * 128]);
#pragma unroll
            for (int mf = 0; mf < 2; ++mf)
#pragma unroll
                for (int nf = 0; nf < 4; ++nf)
                    acc[mf][nf] = __builtin_amdgcn_mfma_f32_16x16x32_f16(aF[mf], bF[nf], acc[mf][nf], 0, 0, 0);
            __syncthreads();
        }

        float sc[4];
#pragma unroll
        for (int nf = 0; nf < 4; ++nf) {
            int col = wc * 64 + nf * 16 + (lane & 15);
            sc[nf] = (mat == 2) ? 1.f : att_l[mat * 128 + col];
        }
#pragma unroll
        for (int mf = 0; mf < 2; ++mf) {
            int row0 = r0 + wr * 32 + mf * 16 + rowq;
#pragma unroll
            for (int reg = 0; reg < 4; ++reg) {
                int row = row0 + reg;
                if (row < NN) {
#pragma unroll
                    for (int nf = 0; nf < 4; ++nf) {
                        int col = wc * 64 + nf * 16 + (lane & 15);
                        float val = acc[mf][nf][reg] * sc[nf];
                        if (mat == 0) {
                            qa[(size_t)row * 128 + col] = __float2half(val);
                        } else if (mat == 1) {
                            kvb[(size_t)row * 384 + col] = f2e4m3(val);
                        } else {
                            *reinterpret_cast<__half*>(kvb + (size_t)row * 384 + 128 + col * 2) = __float2half(val);
                        }
                    }
                }
            }
        }
    }
}

// ---------- CSR build ----------
__global__ __launch_bounds__(256)
void deg_count_kernel(const int* __restrict__ ei, int* __restrict__ deg) {
    int e = blockIdx.x * 256 + threadIdx.x;
    if (e < EE) atomicAdd(&deg[ei[EE + e]], 1);
}

__global__ __launch_bounds__(256)
void scan_partial_kernel(const int* __restrict__ deg, int* __restrict__ psum) {
    __shared__ int red[256];
    int i = blockIdx.x * 256 + threadIdx.x;
    red[threadIdx.x] = (i < NN) ? deg[i] : 0;
    __syncthreads();
    for (int o = 128; o > 0; o >>= 1) {
        if (threadIdx.x < o) red[threadIdx.x] += red[threadIdx.x + o];
        __syncthreads();
    }
    if (threadIdx.x == 0) psum[blockIdx.x] = red[0];
}

// scan_final with fused top-level prefix: block b sums psum[0..b) itself
__global__ __launch_bounds__(256)
void scan_final_kernel(const int* __restrict__ deg, const int* __restrict__ psum,
                       int* __restrict__ offs, int* __restrict__ cursor) {
    __shared__ int red[256];
    __shared__ int sh[256];
    int t = threadIdx.x;
    int b = blockIdx.x;
    red[t] = (t < b) ? psum[t] : 0;   // b <= 195 < 196 entries
    __syncthreads();
    for (int o = 128; o > 0; o >>= 1) {
        if (t < o) red[t] += red[t + o];
        __syncthreads();
    }
    int base = red[0];
    int i = b * 256 + t;
    int v = (i < NN) ? deg[i] : 0;
    sh[t] = v;
    __syncthreads();
    for (int o = 1; o < 256; o <<= 1) {
        int add = (t >= o) ? sh[t - o] : 0;
        __syncthreads();
        sh[t] += add;
        __syncthreads();
    }
    if (i < NN) {
        int excl = sh[t] - v + base;
        offs[i] = excl;
        cursor[i] = excl;
    }
}

// ---------- scatter: single 8B store per edge ----------
__global__ __launch_bounds__(256)
void scatter_kernel(const int* __restrict__ ei, int* __restrict__ cursor,
                    int2* __restrict__ csr) {
    int e = blockIdx.x * 256 + threadIdx.x;
    if (e < EE) {
        int src = ei[e], dst = ei[EE + e];
        int pos = atomicAdd(&cursor[dst], 1);
        csr[pos] = make_int2(src, e);
    }
}

// ---------- eatt build: sequential pos (1 edge/thread), coalesced writes ----------
__global__ __launch_bounds__(256)
void eatt_build_kernel(const float* __restrict__ edge_attr, const int2* __restrict__ csr,
                       const float* __restrict__ M, __half* __restrict__ eatt) {
    __shared__ float Ms[384];
    for (int i = threadIdx.x; i < 384; i += 256) Ms[i] = M[i];
    __syncthreads();
    int pos = blockIdx.x * 256 + threadIdx.x;
    if (pos >= EE) return;
    int e = csr[pos].y;
    const float4* ep = reinterpret_cast<const float4*>(edge_attr + (size_t)e * 16);
    float4 a0 = ep[0], a1 = ep[1], a2 = ep[2], a3 = ep[3];
    float ea[16] = {a0.x, a0.y, a0.z, a0.w, a1.x, a1.y, a1.z, a1.w,
                    a2.x, a2.y, a2.z, a2.w, a3.x, a3.y, a3.z, a3.w};
#pragma unroll
    for (int l = 0; l < 3; ++l) {
        __half o[8] __attribute__((aligned(16)));
#pragma unroll
        for (int h = 0; h < 8; ++h) {
            const float* mp = Ms + l * 128 + h * 16;
            float acc = 0.f;
#pragma unroll
            for (int d = 0; d < 16; ++d) acc += ea[d] * mp[d];
            o[h] = __float2half(acc);
        }
        *reinterpret_cast<uint4*>(eatt + ((size_t)l * EE + pos) * 8) =
            *reinterpret_cast<const uint4*>(o);
    }
}

// ---------- fused attention: fp8 k, fp16 v, direct-exp softmax, 8/4/1 unroll ----------
__global__ __launch_bounds__(128)
void fused_gat_kernel(const __half* __restrict__ qa, const unsigned char* __restrict__ kvb,
                      const __half* __restrict__ eatt_l,
                      const int* __restrict__ offs, const int* __restrict__ deg,
                      const int2* __restrict__ csr, __half* __restrict__ hout) {
    int lane = threadIdx.x & 63;
    int n = blockIdx.x * 2 + (threadIdx.x >> 6);
    if (n >= NN) return;
    int h = lane >> 3;
    int c2h = lane & 7;
    int chh = h * 8 + c2h;

    float2 q = __half22float2(reinterpret_cast<const __half2*>(qa + (size_t)n * 128)[chh]);

    int start = offs[n], d = deg[n];
    const __half* ebase = eatt_l + (size_t)start * 8 + h;
    const int2* cbase = csr + start;

    float den = 0.f, acc0 = 0.f, acc1 = 0.f;
    int i = 0;
    for (; i + 8 <= d; i += 8) {
        int s[8]; float e[8]; uchar2 kr[8]; __half2 vh[8];
#pragma unroll
        for (int j = 0; j < 8; ++j) s[j] = cbase[i + j].x;
#pragma unroll
        for (int j = 0; j < 8; ++j) e[j] = __half2float(ebase[(size_t)(i + j) * 8]);
#pragma unroll
        for (int j = 0; j < 8; ++j) {
            const unsigned char* rp = kvb + (size_t)s[j] * 384;
            kr[j] = *reinterpret_cast<const uchar2*>(rp + (chh << 1));
            vh[j] = *reinterpret_cast<const __half2*>(rp + 128 + (chh << 2));
        }
#pragma unroll
        for (int j = 0; j < 8; ++j) {
            float kx = e4m32f(kr[j].x), ky = e4m32f(kr[j].y);
            float p = q.x * kx + q.y * ky;
            p += __shfl_xor(p, 1); p += __shfl_xor(p, 2); p += __shfl_xor(p, 4);
            float a = p + e[j]; a = a > 0.f ? a : 0.2f * a;
            a = fminf(a, 60.f);
            float w = __expf(a);
            float2 v = __half22float2(vh[j]);
            den += w; acc0 += w * v.x; acc1 += w * v.y;
        }
    }
    for (; i + 4 <= d; i += 4) {
        int s[4]; float e[4]; uchar2 kr[4]; __half2 vh[4];
#pragma unroll
        for (int j = 0; j < 4; ++j) s[j] = cbase[i + j].x;
#pragma unroll
        for (int j = 0; j < 4; ++j) e[j] = __half2float(ebase[(size_t)(i + j) * 8]);
#pragma unroll
        for (int j = 0; j < 4; ++j) {
            const unsigned char* rp = kvb + (size_t)s[j] * 384;
            kr[j] = *reinterpret_cast<const uchar2*>(rp + (chh << 1));
            vh[j] = *reinterpret_cast<const __half2*>(rp + 128 + (chh << 2));
        }
#pragma unroll
        for (int j = 0; j < 4; ++j) {
            float kx = e4m32f(kr[j].x), ky = e4m32f(kr[j].y);
            float p = q.x * kx + q.y * ky;
            p += __shfl_xor(p, 1); p += __shfl_xor(p, 2); p += __shfl_xor(p, 4);
            float a = p + e[j]; a = a > 0.f ? a : 0.2f * a;
            a = fminf(a, 60.f);
            float w = __expf(a);
            float2 v = __half22float2(vh[j]);
            den += w; acc0 += w * v.x; acc1 += w * v.y;
        }
    }
    for (; i < d; ++i) {
        int s0 = cbase[i].x;
        float e0 = __half2float(ebase[(size_t)i * 8]);
        const unsigned char* rp = kvb + (size_t)s0 * 384;
        uchar2 kr = *reinterpret_cast<const uchar2*>(rp + (chh << 1));
        __half2 vh = *reinterpret_cast<const __half2*>(rp + 128 + (chh << 2));
        float kx = e4m32f(kr.x), ky = e4m32f(kr.y);
        float p = q.x * kx + q.y * ky;
        p += __shfl_xor(p, 1); p += __shfl_xor(p, 2); p += __shfl_xor(p, 4);
        float a = p + e0; a = a > 0.f ? a : 0.2f * a;
        a = fminf(a, 60.f);
        float w = __expf(a);
        float2 v = __half22float2(vh);
        den += w; acc0 += w * v.x; acc1 += w * v.y;
    }
    float inv = 1.f / (den + 1e-16f);
    reinterpret_cast<__half2*>(hout + (size_t)n * 128)[chh] =
        __float22half2_rn(make_float2(acc0 * inv, acc1 * inv));
}

// ---------- BN stats (sum, sumsq per channel), fp16 input, uint4 loads ----------
__global__ __launch_bounds__(256)
void bn_stats_kernel(const __half* __restrict__ h, float* __restrict__ sums) {
    __shared__ float red[2][16][128];
    int t = threadIdx.x;
    int cg = t & 15;
    int rofs = t >> 4;
    int r0 = blockIdx.x * 64;
    int rend = min(NN, r0 + 64);
    float s1[8], s2[8];
#pragma unroll
    for (int j = 0; j < 8; ++j) { s1[j] = 0.f; s2[j] = 0.f; }
    for (int r = r0 + rofs; r < rend; r += 16) {
        uint4 raw = *reinterpret_cast<const uint4*>(h + (size_t)r * 128 + cg * 8);
        const __half* rh = reinterpret_cast<const __half*>(&raw);
#pragma unroll
        for (int j = 0; j < 8; ++j) {
            float v = __half2float(rh[j]);
            s1[j] += v; s2[j] += v * v;
        }
    }
#pragma unroll
    for (int j = 0; j < 8; ++j) {
        red[0][rofs][cg * 8 + j] = s1[j];
        red[1][rofs][cg * 8 + j] = s2[j];
    }
    __syncthreads();
    if (t < 128) {
        float a = 0.f, b = 0.f;
#pragma unroll
        for (int i = 0; i < 16; ++i) { a += red[0][i][t]; b += red[1][i][t]; }
        unsafeAtomicAdd(&sums[t], a);
        unsafeAtomicAdd(&sums[128 + t], b);
    }
}

// ---------- last layer: BN apply + segmented global max pool (batch sorted) ----------
__global__ __launch_bounds__(256)
void bn_pool_kernel(const __half* __restrict__ h, const float* __restrict__ sums,
                    const float* __restrict__ scale, const float* __restrict__ shift,
                    const int* __restrict__ batch, unsigned* __restrict__ gkey) {
    int t = threadIdx.x;
    int c = t & 127, half = t >> 7;
    int r0 = blockIdx.x * 32;
    int rend = min(NN, r0 + 32);
    const float invN = 1.f / (float)NN;
    float mu = sums[c] * invN;
    float var = sums[128 + c] * invN - mu * mu;
    float iscl = rsqrtf(var + 1e-5f) * scale[c];
    float sh = shift[c];
    int curg = -1;
    float lmax = -INFINITY;
    for (int r = r0 + half; r < rend; r += 2) {
        int g = batch[r];
        if (g != curg) {
            if (curg >= 0) atomicMax(&gkey[curg * 128 + c], f2key(lmax));
            curg = g;
            lmax = -INFINITY;
        }
        float v = (__half2float(h[(size_t)r * 128 + c]) - mu) * iscl + sh;
        lmax = fmaxf(lmax, v);
    }
    if (curg >= 0) atomicMax(&gkey[curg * 128 + c], f2key(lmax));
}

// ---------- head MLP (single block, 256 threads) ----------
__global__ __launch_bounds__(256)
void head_kernel(const unsigned* __restrict__ gkey,
                 const float* __restrict__ W1, const float* __restrict__ b1,
                 const float* __restrict__ bn1s, const float* __restrict__ bn1b,
                 const float* __restrict__ W2, const float* __restrict__ b2,
                 const float* __restrict__ bn2s, const float* __restrict__ bn2b,
                 const float* __restrict__ Wout, const float* __restrict__ bout,
                 float* __restrict__ out) {
    __shared__ float g[64][128];
    __shared__ float z1[64][64];
    __shared__ float z2[64][32];
    int t = threadIdx.x;
    for (int i = t; i < 64 * 128; i += 256) g[i >> 7][i & 127] = key2f(gkey[i]);
    __syncthreads();
    for (int i = t; i < 64 * 64; i += 256) {
        int r = i >> 6, o = i & 63;
        const float* gr = g[r];
        const float* wr = W1 + (size_t)o * 128;
        float acc = b1[o];
        for (int k2 = 0; k2 < 128; ++k2) acc += gr[k2] * wr[k2];
        z1[r][o] = acc;
    }
    __syncthreads();
    if (t < 64) {
        float s1 = 0.f, s2 = 0.f;
        for (int r = 0; r < 64; ++r) { float v = z1[r][t]; s1 += v; s2 += v * v; }
        float mu = s1 * (1.f / 64.f), var = s2 * (1.f / 64.f) - mu * mu;
        float inv = rsqrtf(var + 1e-5f) * bn1s[t];
        float sh = bn1b[t];
        for (int r = 0; r < 64; ++r) {
            float v = (z1[r][t] - mu) * inv + sh;
            z1[r][t] = v > 0.f ? v : 0.f;
        }
    }
    __syncthreads();
    for (int i = t; i < 64 * 32; i += 256) {
        int r = i >> 5, o = i & 31;
        const float* wr = W2 + (size_t)o * 64;
        float acc = b2[o];
        for (int k2 = 0; k2 < 64; ++k2) acc += z1[r][k2] * wr[k2];
        z2[r][o] = acc;
    }
    __syncthreads();
    if (t < 32) {
        float s1 = 0.f, s2 = 0.f;
        for (int r = 0; r < 64; ++r) { float v = z2[r][t]; s1 += v; s2 += v * v; }
        float mu = s1 * (1.f / 64.f), var = s2 * (1.f / 64.f) - mu * mu;
        float inv = rsqrtf(var + 1e-5f) * bn2s[t];
        float sh = bn2b[t];
        for (int r = 0; r < 64; ++r) {
            float v = (z2[r][t] - mu) * inv + sh;
            z2[r][t] = v > 0.f ? v : 0.f;
        }
    }
    __syncthreads();
    for (int i = t; i < 64 * 64; i += 256) {
        int r = i >> 6, o = i & 63;
        const float* wr = Wout + (size_t)o * 32;
        float acc = bout[o];
        for (int k2 = 0; k2 < 32; ++k2) acc += z2[r][k2] * wr[k2];
        out[r * 64 + o] = acc;
    }
}

extern "C" void kernel_launch(void* const* d_in, const int* in_sizes, int n_in,
                              void* d_out, int out_size, void* d_ws, size_t ws_size,
                              hipStream_t stream) {
    const float* x         = (const float*)d_in[0];
    const int*   ei        = (const int*)d_in[1];
    const float* edge_attr = (const float*)d_in[2];
    const int*   batch     = (const int*)d_in[3];
    const float* lin_qkv   = (const float*)d_in[4];
    const float* lin_edge  = (const float*)d_in[5];
    const float* att       = (const float*)d_in[6];
    // d_in[7] gat_bias: cancels exactly under training-mode BN (mean-subtracted)
    const float* bn_scale  = (const float*)d_in[8];
    const float* bn_bias   = (const float*)d_in[9];
    const float* W1   = (const float*)d_in[10];
    const float* b1   = (const float*)d_in[11];
    const float* bn1s = (const float*)d_in[12];
    const float* bn1b = (const float*)d_in[13];
    const float* W2   = (const float*)d_in[14];
    const float* b2   = (const float*)d_in[15];
    const float* bn2s = (const float*)d_in[16];
    const float* bn2b = (const float*)d_in[17];
    const float* Wout = (const float*)d_in[18];
    const float* bout = (const float*)d_in[19];

    float* ws = (float*)d_ws;
    size_t off = 0;
    auto alloc = [&](size_t n) { float* p = ws + off; off += n; return p; };
    // contiguous zero-region first: deg | gkey | gsums[3][256]
    int*      deg   = (int*)alloc(NN);
    unsigned* gkey  = (unsigned*)alloc(64 * 128);
    float*    gsums = alloc(3 * 256);
    const size_t zeroBytes = ((size_t)NN + 64 * 128 + 3 * 256) * 4;
    __half* hout = (__half*)alloc((size_t)NN * 64);      // NN*128 halves
    __half* qa   = (__half*)alloc((size_t)NN * 64);
    unsigned char* kvb = (unsigned char*)alloc((size_t)NN * 96);  // 384 B/row: k fp8 | v fp16
    __half* Apack = (__half*)alloc((size_t)MB * 8192);   // MB*16384 halves
    __half* Wpack = (__half*)alloc(9 * 8192);            // 9*16384 halves
    int*    offs   = (int*)alloc(NN);
    int*    cursor = (int*)alloc(NN);
    int2*   csr    = (int2*)alloc((size_t)EE * 2);       // (src, eid)
    __half* eatt   = (__half*)alloc((size_t)3 * EE * 4); // [l][EE][8] fp16
    int*    psum   = (int*)alloc(256);
    float*  M      = alloc(3 * 128);

    const int edgeBlocks = (EE + 255) / 256;     // 1563
    const int scanBlocks = (NN + 255) / 256;     // 196
    const int packBlocks = MB * 8;               // 3128
    const int statBlocks = (NN + 63) / 64;       // 782
    const int poolBlocks = (NN + 31) / 32;       // 1563
    const int gatBlocks  = (NN + 1) / 2;         // 25000

    hipMemsetAsync(deg, 0, zeroBytes, stream);
    wpack_kernel<<<72, 256, 0, stream>>>(lin_qkv, Wpack);
    compute_M_kernel<<<2, 256, 0, stream>>>(lin_edge, att, M);
    deg_count_kernel<<<edgeBlocks, 256, 0, stream>>>(ei, deg);
    scan_partial_kernel<<<scanBlocks, 256, 0, stream>>>(deg, psum);
    scan_final_kernel<<<scanBlocks, 256, 0, stream>>>(deg, psum, offs, cursor);
    scatter_kernel<<<edgeBlocks, 256, 0, stream>>>(ei, cursor, csr);
    eatt_build_kernel<<<edgeBlocks, 256, 0, stream>>>(edge_attr, csr, M, eatt);
    pack_x_kernel<<<packBlocks, 256, 0, stream>>>(x, Apack);

    for (int l = 0; l < 3; ++l) {
        qkv_mfma_kernel<<<MB2, 256, 0, stream>>>(
            Apack, Wpack, l, att + (size_t)l * 384, qa, kvb);

        fused_gat_kernel<<<gatBlocks, 128, 0, stream>>>(
            qa, kvb, eatt + (size_t)l * EE * 8, offs, deg, csr, hout);

        bn_stats_kernel<<<statBlocks, 256, 0, stream>>>(hout, gsums + l * 256);

        if (l < 2) {
            pack_h_kernel<<<packBlocks, 256, 0, stream>>>(
                hout, gsums + l * 256, bn_scale + l * 128, bn_bias + l * 128, Apack);
        } else {
            bn_pool_kernel<<<poolBlocks, 256, 0, stream>>>(
                hout, gsums + l * 256, bn_scale + l * 128, bn_bias + l * 128, batch, gkey);
        }
    }

    head_kernel<<<1, 256, 0, stream>>>(gkey, W1, b1, bn1s, bn1b, W2, b2, bn2s, bn2b, Wout, bout, (float*)d_out);
}